// Round 6
// baseline (432.442 us; speedup 1.0000x reference)
//
#include <hip/hip_runtime.h>

typedef unsigned short u16;
typedef unsigned int u32;
typedef __attribute__((ext_vector_type(8))) short bf16x8;   // 8 bf16 = 4 VGPRs (MFMA A/B frag)
typedef __attribute__((ext_vector_type(4))) float f32x4;    // MFMA C/D frag

__device__ __forceinline__ u16 f2bf(float f) {
    u32 u = __float_as_uint(f);
    return (u16)((u + 0x7FFFu + ((u >> 16) & 1u)) >> 16);   // round-to-nearest-even
}

// fast GELU via sigmoid identity: 0.5x(1+tanh(y)) = x*u/(u+1), u=e^{2y}.
__device__ __forceinline__ float fast_gelu(float x) {
    const float t = x * x;
    const float y2 = x * __builtin_fmaf(0.0713548214f, t, 1.5957691216057308f);
    const float u = __expf(fminf(y2, 80.f));                 // overflow-capped
    return x * u * __builtin_amdgcn_rcpf(u + 1.f);
}

// async global->LDS, 16B per lane (dest = uniform base + lane*16, src per-lane)
__device__ __forceinline__ void gload_lds16(const u16* g, u16* l) {
    __builtin_amdgcn_global_load_lds(
        (const __attribute__((address_space(1))) void*)g,
        (__attribute__((address_space(3))) void*)l, 16, 0, 0);
}

// ---------------------------------------------------------------------------
// Prep: cast fp32 -> bf16 streaming (feats / dw_w)
// ---------------------------------------------------------------------------
__global__ __launch_bounds__(256) void cast_feats_k(
    const float* __restrict__ src, u16* __restrict__ dst, int n4)
{
    const int e = blockIdx.x * 256 + threadIdx.x;
    if (e >= n4) return;
    const float4 v = *(const float4*)(src + (size_t)e * 4);
    uint2 o;
    o.x = (u32)f2bf(v.x) | ((u32)f2bf(v.y) << 16);
    o.y = (u32)f2bf(v.z) | ((u32)f2bf(v.w) << 16);
    *(uint2*)(dst + (size_t)e * 4) = o;
}

// ---------------------------------------------------------------------------
// Kernel A: sparse depthwise conv + bias + LayerNorm.  ONE site per wave.
// Ballot/popcount compaction, sentinel-padded unconditional 8-deep batches.
// ---------------------------------------------------------------------------
__global__ __launch_bounds__(256) void dwln_k(
    const u16* __restrict__ featsb, const int* __restrict__ nb,
    const u16* __restrict__ dwwb, const float* __restrict__ dw_b,
    const float* __restrict__ ln_g, const float* __restrict__ ln_b,
    u16* __restrict__ xln, int nsites)
{
    __shared__ int lists[4][352];
    const int w = threadIdx.x >> 6;
    const int lane = threadIdx.x & 63;
    const int s = blockIdx.x * 4 + w;
    if (s >= nsites) return;
    const int* row = nb + (size_t)s * 343;
    int idx[6];
    #pragma unroll
    for (int j = 0; j < 5; ++j) idx[j] = row[lane + j * 64];
    idx[5] = (lane < 23) ? row[320 + lane] : nsites;
    // --- ballot-based compaction: no cross-lane dependency chain ---
    const unsigned long long below = ((1ull << lane) - 1ull);
    int cnt = 0;
    #pragma unroll
    for (int i = 0; i < 6; ++i) {
        const bool v = idx[i] < nsites;
        const unsigned long long bal = __ballot(v);
        const int k = (i < 5) ? (lane + i * 64) : (320 + lane);
        if (v) lists[w][cnt + __popcll(bal & below)] = idx[i] | (k << 17);
        cnt += (int)__popcll(bal);
    }
    // pad to multiple of 8 with sentinel (zero feats row at index nsites)
    const int cntp = (cnt + 7) & ~7;
    if (lane < cntp - cnt) lists[w][cnt + lane] = nsites;    // k=0, row is zero
    __builtin_amdgcn_s_waitcnt(0);                            // lds writes visible (wave-private)
    float x0 = 0.f, x1 = 0.f;
    for (int base = 0; base < cntp; base += 8) {
        u32 f[8], wv[8];
        #pragma unroll
        for (int i = 0; i < 8; ++i) {
            const int e = lists[w][base + i];
            f[i]  = *(const u32*)(featsb + (size_t)(e & 0x1FFFF) * 128 + lane * 2);
            wv[i] = *(const u32*)(dwwb + (size_t)(e >> 17) * 128 + lane * 2);
        }
        #pragma unroll
        for (int i = 0; i < 8; ++i) {
            x0 += __uint_as_float(f[i] << 16) * __uint_as_float(wv[i] << 16);
            x1 += __uint_as_float(f[i] & 0xFFFF0000u) * __uint_as_float(wv[i] & 0xFFFF0000u);
        }
    }
    const float2 bv = *(const float2*)(dw_b + lane * 2);
    const float2 gv = *(const float2*)(ln_g + lane * 2);
    const float2 lbv = *(const float2*)(ln_b + lane * 2);
    float a0 = x0 + bv.x, a1 = x1 + bv.y;
    float sm = a0 + a1, ss = a0 * a0 + a1 * a1;
    #pragma unroll
    for (int off = 32; off > 0; off >>= 1) {
        sm += __shfl_xor(sm, off, 64);
        ss += __shfl_xor(ss, off, 64);
    }
    const float mean = sm * (1.f / 128.f);
    const float var = ss * (1.f / 128.f) - mean * mean;
    const float rstd = rsqrtf(fmaxf(var, 0.f) + 1e-6f);
    const float y0 = (a0 - mean) * rstd * gv.x + lbv.x;
    const float y1 = (a1 - mean) * rstd * gv.y + lbv.y;
    *(u32*)(xln + (size_t)s * 128 + lane * 2) =
        (u32)f2bf(y0) | ((u32)f2bf(y1) << 16);
}

// ---------------------------------------------------------------------------
// w1 fp32 [128,512] -> w1t bf16 [512,128] (channel-major for MFMA frag reads)
// ---------------------------------------------------------------------------
__global__ __launch_bounds__(256) void transpose_w1_k(
    const float* __restrict__ w1, u16* __restrict__ w1t)
{
    const int e = blockIdx.x * 256 + threadIdx.x;    // 65536 total
    const int n = e >> 7, k = e & 127;
    w1t[e] = f2bf(w1[k * 512 + n]);
}

// ---------------------------------------------------------------------------
// Kernel B: h = gelu(xln @ w1 + b1) [N,512] bf16 + per-channel sum(h^2).
// OPERAND-SWAPPED MFMA (A=w1t channel rows from L2, B=xln site rows).
// xln tile staged once via global_load_lds, XOR-swizzled source.
// (256,8): 8 blocks/CU resident (VGPR 40<=64, LDS 8x16.9KB=135KB<160KB) --
// phases of concurrent blocks overlap (VALU epilogue under MFMA/stage).
// ---------------------------------------------------------------------------
__global__ __launch_bounds__(256, 8) void gemm1_k(
    const u16* __restrict__ xln, const u16* __restrict__ w1t,
    const float* __restrict__ b1, u16* __restrict__ h,
    float* __restrict__ gx_sq, int nsites)
{
    __shared__ u16 xb[64 * 128];         // [site r][stored chunk s], s = c ^ (r&15)
    __shared__ float s_red[128];
    const int t = threadIdx.x;
    const int n0 = blockIdx.x * 128;     // channel block
    const int m0 = blockIdx.y * 64;      // site block
    const int lane = t & 63;
    const int w = t >> 6;
    const int wn = w * 32;               // wave's 32-channel slice
    const int l15 = lane & 15, quad = lane >> 4;
    if (t < 128) s_red[t] = 0.f;
    // --- stage xln tile: 4 instrs/wave, each covers 4 rows (1 KB) ---
    #pragma unroll
    for (int i = 0; i < 4; ++i) {
        const int r = w * 16 + i * 4 + (lane >> 4);          // tile row this lane loads
        const int c = (lane & 15) ^ (r & 15);                // logical chunk for stored slot
        gload_lds16(xln + (size_t)(m0 + r) * 128 + c * 8,
                    &xb[(w * 16 + i * 4) * 128]);
    }
    f32x4 acc[2][4];                     // [nt (chan 16-grp)][mt (site 16-grp)]
    #pragma unroll
    for (int i = 0; i < 2; ++i)
        #pragma unroll
        for (int j = 0; j < 4; ++j) acc[i][j] = f32x4{0.f, 0.f, 0.f, 0.f};
    const u16* a_base = w1t + (size_t)(n0 + wn + l15) * 128 + quad * 8;  // channel rows (L2-hot)
    bf16x8 aC[2];
    #pragma unroll
    for (int nt = 0; nt < 2; ++nt) aC[nt] = *(const bf16x8*)(a_base + (size_t)nt * 16 * 128);
    asm volatile("s_waitcnt vmcnt(0)" ::: "memory");
    __syncthreads();                     // tile landed for all waves
    #pragma unroll
    for (int ks = 0; ks < 4; ++ks) {
        bf16x8 aN[2];
        if (ks < 3) {
            #pragma unroll
            for (int nt = 0; nt < 2; ++nt)
                aN[nt] = *(const bf16x8*)(a_base + (size_t)nt * 16 * 128 + (ks + 1) * 32);
        }
        bf16x8 b[4];
        #pragma unroll
        for (int mt = 0; mt < 4; ++mt) {
            const int r = mt * 16 + l15;
            b[mt] = *(const bf16x8*)(&xb[r * 128 + (((ks * 4 + quad) ^ l15) << 3)]);
        }
        #pragma unroll
        for (int nt = 0; nt < 2; ++nt)
            #pragma unroll
            for (int mt = 0; mt < 4; ++mt)
                acc[nt][mt] = __builtin_amdgcn_mfma_f32_16x16x32_bf16(aC[nt], b[mt], acc[nt][mt], 0, 0, 0);
        if (ks < 3) {
            #pragma unroll
            for (int nt = 0; nt < 2; ++nt) aC[nt] = aN[nt];
        }
    }
    // epilogue: lane holds channels chb..chb+3 (consecutive) for site m0+mt*16+l15
    float ssl[2][4] = {{0.f,0.f,0.f,0.f},{0.f,0.f,0.f,0.f}};
    #pragma unroll
    for (int nt = 0; nt < 2; ++nt) {
        const int chb = n0 + wn + nt * 16 + quad * 4;        // global channel base
        const float4 b1v = *(const float4*)(b1 + chb);
        #pragma unroll
        for (int mt = 0; mt < 4; ++mt) {
            const int site = m0 + mt * 16 + l15;
            if (site < nsites) {
                float v[4];
                #pragma unroll
                for (int rg = 0; rg < 4; ++rg) {
                    v[rg] = fast_gelu(acc[nt][mt][rg] + ((const float*)&b1v)[rg]);
                    ssl[nt][rg] += v[rg] * v[rg];
                }
                uint2 o;
                o.x = (u32)f2bf(v[0]) | ((u32)f2bf(v[1]) << 16);
                o.y = (u32)f2bf(v[2]) | ((u32)f2bf(v[3]) << 16);
                *(uint2*)(h + (size_t)site * 512 + chb) = o;
            }
        }
    }
    // reduce ssl over the 16 l15-lanes (same channel), then 4 lanes/wave do LDS atomics
    #pragma unroll
    for (int nt = 0; nt < 2; ++nt)
        #pragma unroll
        for (int rg = 0; rg < 4; ++rg) {
            float v = ssl[nt][rg];
            v += __shfl_xor(v, 1, 64);
            v += __shfl_xor(v, 2, 64);
            v += __shfl_xor(v, 4, 64);
            v += __shfl_xor(v, 8, 64);
            if (l15 == 0) atomicAdd(&s_red[wn + nt * 16 + quad * 4 + rg], v);
        }
    __syncthreads();
    if (t < 128) atomicAdd(&gx_sq[n0 + t], s_red[t]);
}

// ---------------------------------------------------------------------------
// Kernel C0: b_eff_acc = grn_b @ w2
// ---------------------------------------------------------------------------
__global__ __launch_bounds__(256) void beff_k(
    const float* __restrict__ grn_b, const float* __restrict__ w2,
    float* __restrict__ b_eff)
{
    __shared__ float red[256];
    const int t = threadIdx.x;
    const int dc = t & 127, part = t >> 7;
    const int c0 = blockIdx.x * 64 + part * 32;
    float p = 0.f;
    #pragma unroll 8
    for (int i = 0; i < 32; ++i) {
        const int c = c0 + i;
        p += grn_b[c] * w2[(size_t)c * 128 + dc];
    }
    red[t] = p;
    __syncthreads();
    if (t < 128) atomicAdd(&b_eff[t], red[t] + red[t + 128]);
}

// ---------------------------------------------------------------------------
// Kernel C1: GRN scale only (one tiny block).
// ---------------------------------------------------------------------------
__global__ __launch_bounds__(512) void grn_scale_k(
    const float* __restrict__ gx_sq, const float* __restrict__ grn_g,
    float* __restrict__ scale)
{
    __shared__ float red[512];
    const int t = threadIdx.x;
    const float g = sqrtf(gx_sq[t]);
    red[t] = g;
    __syncthreads();
    #pragma unroll
    for (int off = 256; off > 0; off >>= 1) {
        if (t < off) red[t] += red[t + off];
        __syncthreads();
    }
    const float mean = red[0] * (1.f / 512.f);
    scale[t] = grn_g[t] * (g / (mean + 1e-6f)) + 1.f;
}

// ---------------------------------------------------------------------------
// Kernel C2: w2t[dc][c] = bf16(scale[c] * w2[c][dc])  (coalesced writes)
// ---------------------------------------------------------------------------
__global__ __launch_bounds__(256) void w2t_k(
    const float* __restrict__ scale, const float* __restrict__ w2,
    u16* __restrict__ w2t)
{
    const int e = blockIdx.x * 256 + threadIdx.x;    // 65536
    const int c = e & 511, dc = e >> 9;
    w2t[e] = f2bf(scale[c] * w2[(size_t)c * 128 + dc]);
}

// ---------------------------------------------------------------------------
// Kernel D: out = feats + h_scaled @ w2 + b_eff + b2 (fp32 out).
// OPERAND-SWAPPED (A=w2t out-channel rows from L2, B=h site rows).
// h streamed through LDS in 4 K-chunks (double-buffered).
// (256,5): 5 blocks/CU -- exactly fills 160KB LDS (5 x 32KB).
// ---------------------------------------------------------------------------
__global__ __launch_bounds__(256, 5) void gemm2_k(
    const u16* __restrict__ h, const u16* __restrict__ w2t,
    const float* __restrict__ b_eff, const float* __restrict__ b2,
    const float* __restrict__ feats,
    float* __restrict__ out, int nsites)
{
    __shared__ u16 hb[2][64 * 128];      // double-buffered K-chunk tile
    const int t = threadIdx.x;
    const int m0 = blockIdx.x * 64;
    const int lane = t & 63;
    const int w = t >> 6;
    const int wn = w * 32;               // wave's 32 output channels
    const int l15 = lane & 15, quad = lane >> 4;
    f32x4 acc[2][4];                     // [nt (out-chan 16-grp)][mt (site 16-grp)]
    #pragma unroll
    for (int i = 0; i < 2; ++i)
        #pragma unroll
        for (int j = 0; j < 4; ++j) acc[i][j] = f32x4{0.f, 0.f, 0.f, 0.f};
    const u16* a_base = w2t + (size_t)(wn + l15) * 512 + quad * 8;   // out-channel rows (L2-hot)

    // stage chunk tc (K cols [tc*128, tc*128+128)) into buffer b
    #define STAGE2(bsel, tc)                                                     \
        {                                                                        \
            _Pragma("unroll")                                                    \
            for (int i_ = 0; i_ < 4; ++i_) {                                     \
                const int r_ = w * 16 + i_ * 4 + (lane >> 4);                    \
                const int c_ = (lane & 15) ^ (r_ & 15);                          \
                gload_lds16(h + (size_t)(m0 + r_) * 512 + (tc) * 128 + c_ * 8,   \
                            &hb[bsel][(w * 16 + i_ * 4) * 128]);                 \
            }                                                                    \
        }

    STAGE2(0, 0)
    bf16x8 aC[2];
    #pragma unroll
    for (int nt = 0; nt < 2; ++nt) aC[nt] = *(const bf16x8*)(a_base + (size_t)nt * 16 * 512);
    asm volatile("s_waitcnt vmcnt(0)" ::: "memory");
    __syncthreads();
    #pragma unroll
    for (int tch = 0; tch < 4; ++tch) {
        const int cur = tch & 1;
        if (tch < 3) STAGE2(cur ^ 1, tch + 1)
        #pragma unroll
        for (int ks = 0; ks < 4; ++ks) {
            const int ksg = tch * 4 + ks;
            bf16x8 aN[2];
            if (ksg < 15) {
                #pragma unroll
                for (int nt = 0; nt < 2; ++nt)
                    aN[nt] = *(const bf16x8*)(a_base + (size_t)nt * 16 * 512 + (ksg + 1) * 32);
            }
            bf16x8 b[4];
            #pragma unroll
            for (int mt = 0; mt < 4; ++mt) {
                const int r = mt * 16 + l15;
                b[mt] = *(const bf16x8*)(&hb[cur][r * 128 + (((ks * 4 + quad) ^ l15) << 3)]);
            }
            #pragma unroll
            for (int nt = 0; nt < 2; ++nt)
                #pragma unroll
                for (int mt = 0; mt < 4; ++mt)
                    acc[nt][mt] = __builtin_amdgcn_mfma_f32_16x16x32_bf16(aC[nt], b[mt], acc[nt][mt], 0, 0, 0);
            if (ksg < 15) {
                #pragma unroll
                for (int nt = 0; nt < 2; ++nt) aC[nt] = aN[nt];
            }
        }
        if (tch < 3) {
            asm volatile("s_waitcnt vmcnt(0)" ::: "memory");
            __syncthreads();             // next chunk landed (all waves)
        }
    }
    #undef STAGE2
    // epilogue: lane holds out-channels chb..chb+3 for site m0+mt*16+l15
    #pragma unroll
    for (int nt = 0; nt < 2; ++nt) {
        const int chb = wn + nt * 16 + quad * 4;
        const float4 bev = *(const float4*)(b_eff + chb);
        const float4 b2v = *(const float4*)(b2 + chb);
        #pragma unroll
        for (int mt = 0; mt < 4; ++mt) {
            const int site = m0 + mt * 16 + l15;
            if (site < nsites) {
                const float4 fv = *(const float4*)(feats + (size_t)site * 128 + chb);
                float4 o;
                o.x = acc[nt][mt][0] + bev.x + b2v.x + fv.x;
                o.y = acc[nt][mt][1] + bev.y + b2v.y + fv.y;
                o.z = acc[nt][mt][2] + bev.z + b2v.z + fv.z;
                o.w = acc[nt][mt][3] + bev.w + b2v.w + fv.w;
                *(float4*)(out + (size_t)site * 128 + chb) = o;
            }
        }
    }
}

// ---------------------------------------------------------------------------
extern "C" void kernel_launch(void* const* d_in, const int* in_sizes, int n_in,
                              void* d_out, int out_size, void* d_ws, size_t ws_size,
                              hipStream_t stream) {
    const float* feats = (const float*)d_in[0];    // [N,128] f32
    const int* nb      = (const int*)d_in[1];      // [N,343] int32
    const float* dw_w  = (const float*)d_in[2];    // [343,128] f32
    const float* dw_b  = (const float*)d_in[3];    // [128]
    const float* ln_g  = (const float*)d_in[4];    // [128]
    const float* ln_b  = (const float*)d_in[5];    // [128]
    const float* w1    = (const float*)d_in[6];    // [128,512]
    const float* b1    = (const float*)d_in[7];    // [512]
    const float* grn_g = (const float*)d_in[8];    // [512]
    const float* grn_b = (const float*)d_in[9];    // [512]
    const float* w2    = (const float*)d_in[10];   // [512,128]
    const float* b2    = (const float*)d_in[11];   // [128]
    float* out = (float*)d_out;
    const int nsites = in_sizes[0] / 128;

    char* ws = (char*)d_ws;
    size_t off = 0;
    u16* xln   = (u16*)(ws + off);  off += (((size_t)(nsites + 128) * 128 * 2) + 255) & ~(size_t)255;
    u16* h     = (u16*)(ws + off);  off += (((size_t)(nsites + 128) * 512 * 2) + 255) & ~(size_t)255;
    u16* featsb= (u16*)(ws + off);  off += (((size_t)(nsites + 1) * 128 * 2) + 255) & ~(size_t)255;
    u16* dwwb  = (u16*)(ws + off);  off += 343 * 128 * 2 + 128;
    u16* w1t   = (u16*)(ws + off);  off += 512 * 128 * 2;
    u16* w2t   = (u16*)(ws + off);  off += 128 * 512 * 2;
    float* gx_sq = (float*)(ws + off); off += 512 * 4;
    float* scale = (float*)(ws + off); off += 512 * 4;
    float* b_eff = (float*)(ws + off); off += 128 * 4;

    hipMemsetAsync(gx_sq, 0, 512 * sizeof(float), stream);
    hipMemsetAsync(b_eff, 0, 128 * sizeof(float), stream);
    hipMemsetAsync(featsb + (size_t)nsites * 128, 0, 128 * sizeof(u16), stream);  // zero sentinel row
    const int nfeat4 = nsites * 32;
    cast_feats_k<<<(nfeat4 + 255) / 256, 256, 0, stream>>>(feats, featsb, nfeat4);
    const int ndww4 = 343 * 32;
    cast_feats_k<<<(ndww4 + 255) / 256, 256, 0, stream>>>(dw_w, dwwb, ndww4);
    transpose_w1_k<<<256, 256, 0, stream>>>(w1, w1t);
    beff_k<<<8, 256, 0, stream>>>(grn_b, w2, b_eff);
    dwln_k<<<(nsites + 3) / 4, 256, 0, stream>>>(featsb, nb, dwwb, dw_b, ln_g, ln_b, xln, nsites);
    const int m1blocks = (nsites + 63) / 64;
    gemm1_k<<<dim3(4, m1blocks), 256, 0, stream>>>(xln, w1t, b1, h, gx_sq, nsites);
    grn_scale_k<<<1, 512, 0, stream>>>(gx_sq, grn_g, scale);
    w2t_k<<<256, 256, 0, stream>>>(scale, w2, w2t);
    const int m2blocks = (nsites + 63) / 64;
    gemm2_k<<<m2blocks, 256, 0, stream>>>(h, w2t, b_eff, b2, feats, out, nsites);
}

// Round 7
// 404.091 us; speedup vs baseline: 1.0702x; 1.0702x over previous
//
#include <hip/hip_runtime.h>

typedef unsigned short u16;
typedef unsigned int u32;
typedef __attribute__((ext_vector_type(8))) short bf16x8;   // 8 bf16 = 4 VGPRs (MFMA A/B frag)
typedef __attribute__((ext_vector_type(4))) float f32x4;    // MFMA C/D frag

__device__ __forceinline__ u16 f2bf(float f) {
    u32 u = __float_as_uint(f);
    return (u16)((u + 0x7FFFu + ((u >> 16) & 1u)) >> 16);   // round-to-nearest-even
}

// fast GELU via sigmoid identity: 0.5x(1+tanh(y)) = x*u/(u+1), u=e^{2y}.
__device__ __forceinline__ float fast_gelu(float x) {
    const float t = x * x;
    const float y2 = x * __builtin_fmaf(0.0713548214f, t, 1.5957691216057308f);
    const float u = __expf(fminf(y2, 80.f));                 // overflow-capped
    return x * u * __builtin_amdgcn_rcpf(u + 1.f);
}

// async global->LDS, 16B per lane (dest = uniform base + lane*16, src per-lane)
__device__ __forceinline__ void gload_lds16(const u16* g, u16* l) {
    __builtin_amdgcn_global_load_lds(
        (const __attribute__((address_space(1))) void*)g,
        (__attribute__((address_space(3))) void*)l, 16, 0, 0);
}

// ---------------------------------------------------------------------------
// Prep: cast fp32 -> bf16 streaming (feats / dw_w)
// ---------------------------------------------------------------------------
__global__ __launch_bounds__(256) void cast_feats_k(
    const float* __restrict__ src, u16* __restrict__ dst, int n4)
{
    const int e = blockIdx.x * 256 + threadIdx.x;
    if (e >= n4) return;
    const float4 v = *(const float4*)(src + (size_t)e * 4);
    uint2 o;
    o.x = (u32)f2bf(v.x) | ((u32)f2bf(v.y) << 16);
    o.y = (u32)f2bf(v.z) | ((u32)f2bf(v.w) << 16);
    *(uint2*)(dst + (size_t)e * 4) = o;
}

// ---------------------------------------------------------------------------
// Kernel A: sparse depthwise conv + bias + LayerNorm.  ONE site per wave.
// Ballot/popcount compaction, sentinel-padded unconditional 8-deep batches.
// ---------------------------------------------------------------------------
__global__ __launch_bounds__(256) void dwln_k(
    const u16* __restrict__ featsb, const int* __restrict__ nb,
    const u16* __restrict__ dwwb, const float* __restrict__ dw_b,
    const float* __restrict__ ln_g, const float* __restrict__ ln_b,
    u16* __restrict__ xln, int nsites)
{
    __shared__ int lists[4][352];
    const int w = threadIdx.x >> 6;
    const int lane = threadIdx.x & 63;
    const int s = blockIdx.x * 4 + w;
    if (s >= nsites) return;
    const int* row = nb + (size_t)s * 343;
    int idx[6];
    #pragma unroll
    for (int j = 0; j < 5; ++j) idx[j] = row[lane + j * 64];
    idx[5] = (lane < 23) ? row[320 + lane] : nsites;
    // --- ballot-based compaction: no cross-lane dependency chain ---
    const unsigned long long below = ((1ull << lane) - 1ull);
    int cnt = 0;
    #pragma unroll
    for (int i = 0; i < 6; ++i) {
        const bool v = idx[i] < nsites;
        const unsigned long long bal = __ballot(v);
        const int k = (i < 5) ? (lane + i * 64) : (320 + lane);
        if (v) lists[w][cnt + __popcll(bal & below)] = idx[i] | (k << 17);
        cnt += (int)__popcll(bal);
    }
    // pad to multiple of 8 with sentinel (zero feats row at index nsites)
    const int cntp = (cnt + 7) & ~7;
    if (lane < cntp - cnt) lists[w][cnt + lane] = nsites;    // k=0, row is zero
    __builtin_amdgcn_s_waitcnt(0);                            // lds writes visible (wave-private)
    float x0 = 0.f, x1 = 0.f;
    for (int base = 0; base < cntp; base += 8) {
        u32 f[8], wv[8];
        #pragma unroll
        for (int i = 0; i < 8; ++i) {
            const int e = lists[w][base + i];
            f[i]  = *(const u32*)(featsb + (size_t)(e & 0x1FFFF) * 128 + lane * 2);
            wv[i] = *(const u32*)(dwwb + (size_t)(e >> 17) * 128 + lane * 2);
        }
        #pragma unroll
        for (int i = 0; i < 8; ++i) {
            x0 += __uint_as_float(f[i] << 16) * __uint_as_float(wv[i] << 16);
            x1 += __uint_as_float(f[i] & 0xFFFF0000u) * __uint_as_float(wv[i] & 0xFFFF0000u);
        }
    }
    const float2 bv = *(const float2*)(dw_b + lane * 2);
    const float2 gv = *(const float2*)(ln_g + lane * 2);
    const float2 lbv = *(const float2*)(ln_b + lane * 2);
    float a0 = x0 + bv.x, a1 = x1 + bv.y;
    float sm = a0 + a1, ss = a0 * a0 + a1 * a1;
    #pragma unroll
    for (int off = 32; off > 0; off >>= 1) {
        sm += __shfl_xor(sm, off, 64);
        ss += __shfl_xor(ss, off, 64);
    }
    const float mean = sm * (1.f / 128.f);
    const float var = ss * (1.f / 128.f) - mean * mean;
    const float rstd = rsqrtf(fmaxf(var, 0.f) + 1e-6f);
    const float y0 = (a0 - mean) * rstd * gv.x + lbv.x;
    const float y1 = (a1 - mean) * rstd * gv.y + lbv.y;
    *(u32*)(xln + (size_t)s * 128 + lane * 2) =
        (u32)f2bf(y0) | ((u32)f2bf(y1) << 16);
}

// ---------------------------------------------------------------------------
// w1 fp32 [128,512] -> w1t bf16 [512,128] (channel-major for MFMA frag reads)
// ---------------------------------------------------------------------------
__global__ __launch_bounds__(256) void transpose_w1_k(
    const float* __restrict__ w1, u16* __restrict__ w1t)
{
    const int e = blockIdx.x * 256 + threadIdx.x;    // 65536 total
    const int n = e >> 7, k = e & 127;
    w1t[e] = f2bf(w1[k * 512 + n]);
}

// ---------------------------------------------------------------------------
// Kernel B: h = gelu(xln @ w1 + b1) [N,512] bf16 + per-channel sum(h^2).
// PERSISTENT m-tile pipeline: each block owns channel slice n0 and loops
// m-tiles (stride gridDim.y) with double-buffered LDS.  stage(t+1) issued
// right after the top barrier -> HBM latency hides under tile t's MFMA +
// gelu epilogue.  Counted s_waitcnt vmcnt(8) + RAW s_barrier (not
// __syncthreads: that drains vmcnt(0) incl. in-flight h-stores).
// A-fragments (w1t) hoisted: loaded once per block.
// ---------------------------------------------------------------------------
__global__ __launch_bounds__(256, 4) void gemm1_k(
    const u16* __restrict__ xln, const u16* __restrict__ w1t,
    const float* __restrict__ b1, u16* __restrict__ h,
    float* __restrict__ gx_sq, int nsites, int nmb)
{
    __shared__ u16 xb[2][64 * 128];      // double-buffered site tile (swizzled)
    __shared__ float s_red[128];
    const int t = threadIdx.x;
    const int n0 = blockIdx.x * 128;     // channel block
    const int lane = t & 63;
    const int w = t >> 6;
    const int wn = w * 32;               // wave's 32-channel slice
    const int l15 = lane & 15, quad = lane >> 4;
    if (t < 128) s_red[t] = 0.f;

    // stage m-tile mb into buffer bsel (pre-swizzled source, linear LDS dest)
    #define STAGE1(bsel, mb_)                                                    \
        {                                                                        \
            _Pragma("unroll")                                                    \
            for (int i_ = 0; i_ < 4; ++i_) {                                     \
                const int r_ = w * 16 + i_ * 4 + (lane >> 4);                    \
                const int c_ = (lane & 15) ^ (r_ & 15);                          \
                gload_lds16(xln + (size_t)((mb_) * 64 + r_) * 128 + c_ * 8,      \
                            &xb[bsel][(w * 16 + i_ * 4) * 128]);                 \
            }                                                                    \
        }

    int mb = blockIdx.y;
    STAGE1(0, mb)                                 // prologue stage (oldest VMEM!)
    __builtin_amdgcn_sched_barrier(0);            // pin: stage before A-loads
    // hoist ALL A fragments for this channel slice (invariant over m-tiles)
    const u16* a_base = w1t + (size_t)(n0 + wn + l15) * 128 + quad * 8;
    bf16x8 aF[4][2];
    #pragma unroll
    for (int ks = 0; ks < 4; ++ks)
        #pragma unroll
        for (int nt = 0; nt < 2; ++nt)
            aF[ks][nt] = *(const bf16x8*)(a_base + (size_t)nt * 16 * 128 + ks * 32);

    float ssl[2][4] = {{0.f,0.f,0.f,0.f},{0.f,0.f,0.f,0.f}};
    int cur = 0;
    while (mb < nmb) {
        // wait ONLY the 4 stage loads (oldest); epilogue stores stay in flight
        asm volatile("s_waitcnt vmcnt(8)" ::: "memory");
        __builtin_amdgcn_s_barrier();
        __builtin_amdgcn_sched_barrier(0);
        const int mbn = mb + (int)gridDim.y;
        if (mbn < nmb) STAGE1(cur ^ 1, mbn)       // prefetch next tile
        __builtin_amdgcn_sched_barrier(0);        // pin: stage before ds/MFMA/stores
        const int m0 = mb * 64;
        f32x4 acc[2][4];
        #pragma unroll
        for (int i = 0; i < 2; ++i)
            #pragma unroll
            for (int j = 0; j < 4; ++j) acc[i][j] = f32x4{0.f, 0.f, 0.f, 0.f};
        #pragma unroll
        for (int ks = 0; ks < 4; ++ks) {
            bf16x8 b[4];
            #pragma unroll
            for (int mt = 0; mt < 4; ++mt) {
                const int r = mt * 16 + l15;
                b[mt] = *(const bf16x8*)(&xb[cur][r * 128 + (((ks * 4 + quad) ^ l15) << 3)]);
            }
            #pragma unroll
            for (int nt = 0; nt < 2; ++nt)
                #pragma unroll
                for (int mt = 0; mt < 4; ++mt)
                    acc[nt][mt] = __builtin_amdgcn_mfma_f32_16x16x32_bf16(aF[ks][nt], b[mt], acc[nt][mt], 0, 0, 0);
        }
        // epilogue: gelu + pack + store (8 x 8B stores); ssl accumulates
        #pragma unroll
        for (int nt = 0; nt < 2; ++nt) {
            const int chb = n0 + wn + nt * 16 + quad * 4;
            const float4 b1v = *(const float4*)(b1 + chb);
            #pragma unroll
            for (int mt = 0; mt < 4; ++mt) {
                const int site = m0 + mt * 16 + l15;
                if (site < nsites) {
                    float v[4];
                    #pragma unroll
                    for (int rg = 0; rg < 4; ++rg) {
                        v[rg] = fast_gelu(acc[nt][mt][rg] + ((const float*)&b1v)[rg]);
                        ssl[nt][rg] += v[rg] * v[rg];
                    }
                    uint2 o;
                    o.x = (u32)f2bf(v[0]) | ((u32)f2bf(v[1]) << 16);
                    o.y = (u32)f2bf(v[2]) | ((u32)f2bf(v[3]) << 16);
                    *(uint2*)(h + (size_t)site * 512 + chb) = o;
                }
            }
        }
        mb = mbn; cur ^= 1;
    }
    #undef STAGE1
    // once-per-block gx_sq reduction
    #pragma unroll
    for (int nt = 0; nt < 2; ++nt)
        #pragma unroll
        for (int rg = 0; rg < 4; ++rg) {
            float v = ssl[nt][rg];
            v += __shfl_xor(v, 1, 64);
            v += __shfl_xor(v, 2, 64);
            v += __shfl_xor(v, 4, 64);
            v += __shfl_xor(v, 8, 64);
            if (l15 == 0) atomicAdd(&s_red[wn + nt * 16 + quad * 4 + rg], v);
        }
    __syncthreads();
    if (t < 128) atomicAdd(&gx_sq[n0 + t], s_red[t]);
}

// ---------------------------------------------------------------------------
// Kernel C0: b_eff_acc = grn_b @ w2
// ---------------------------------------------------------------------------
__global__ __launch_bounds__(256) void beff_k(
    const float* __restrict__ grn_b, const float* __restrict__ w2,
    float* __restrict__ b_eff)
{
    __shared__ float red[256];
    const int t = threadIdx.x;
    const int dc = t & 127, part = t >> 7;
    const int c0 = blockIdx.x * 64 + part * 32;
    float p = 0.f;
    #pragma unroll 8
    for (int i = 0; i < 32; ++i) {
        const int c = c0 + i;
        p += grn_b[c] * w2[(size_t)c * 128 + dc];
    }
    red[t] = p;
    __syncthreads();
    if (t < 128) atomicAdd(&b_eff[t], red[t] + red[t + 128]);
}

// ---------------------------------------------------------------------------
// Kernel C1: GRN scale only (one tiny block).
// ---------------------------------------------------------------------------
__global__ __launch_bounds__(512) void grn_scale_k(
    const float* __restrict__ gx_sq, const float* __restrict__ grn_g,
    float* __restrict__ scale)
{
    __shared__ float red[512];
    const int t = threadIdx.x;
    const float g = sqrtf(gx_sq[t]);
    red[t] = g;
    __syncthreads();
    #pragma unroll
    for (int off = 256; off > 0; off >>= 1) {
        if (t < off) red[t] += red[t + off];
        __syncthreads();
    }
    const float mean = red[0] * (1.f / 512.f);
    scale[t] = grn_g[t] * (g / (mean + 1e-6f)) + 1.f;
}

// ---------------------------------------------------------------------------
// Kernel C2: w2t[dc][c] = bf16(scale[c] * w2[c][dc])  (coalesced writes)
// ---------------------------------------------------------------------------
__global__ __launch_bounds__(256) void w2t_k(
    const float* __restrict__ scale, const float* __restrict__ w2,
    u16* __restrict__ w2t)
{
    const int e = blockIdx.x * 256 + threadIdx.x;    // 65536
    const int c = e & 511, dc = e >> 9;
    w2t[e] = f2bf(scale[c] * w2[(size_t)c * 128 + dc]);
}

// ---------------------------------------------------------------------------
// Kernel D: out = feats + h_scaled @ w2 + b_eff + b2 (fp32 out).
// OPERAND-SWAPPED (A=w2t out-channel rows from L2, B=h site rows).
// h streamed through LDS in 4 K-chunks (double-buffered).  (256,4): the
// round-5 verified config (256,5 suspected of VGPR squeeze in round 6).
// ---------------------------------------------------------------------------
__global__ __launch_bounds__(256, 4) void gemm2_k(
    const u16* __restrict__ h, const u16* __restrict__ w2t,
    const float* __restrict__ b_eff, const float* __restrict__ b2,
    const float* __restrict__ feats,
    float* __restrict__ out, int nsites)
{
    __shared__ u16 hb[2][64 * 128];      // double-buffered K-chunk tile
    const int t = threadIdx.x;
    const int m0 = blockIdx.x * 64;
    const int lane = t & 63;
    const int w = t >> 6;
    const int wn = w * 32;               // wave's 32 output channels
    const int l15 = lane & 15, quad = lane >> 4;
    f32x4 acc[2][4];                     // [nt (out-chan 16-grp)][mt (site 16-grp)]
    #pragma unroll
    for (int i = 0; i < 2; ++i)
        #pragma unroll
        for (int j = 0; j < 4; ++j) acc[i][j] = f32x4{0.f, 0.f, 0.f, 0.f};
    const u16* a_base = w2t + (size_t)(wn + l15) * 512 + quad * 8;   // out-channel rows (L2-hot)

    // stage chunk tc (K cols [tc*128, tc*128+128)) into buffer b
    #define STAGE2(bsel, tc)                                                     \
        {                                                                        \
            _Pragma("unroll")                                                    \
            for (int i_ = 0; i_ < 4; ++i_) {                                     \
                const int r_ = w * 16 + i_ * 4 + (lane >> 4);                    \
                const int c_ = (lane & 15) ^ (r_ & 15);                          \
                gload_lds16(h + (size_t)(m0 + r_) * 512 + (tc) * 128 + c_ * 8,   \
                            &hb[bsel][(w * 16 + i_ * 4) * 128]);                 \
            }                                                                    \
        }

    STAGE2(0, 0)
    bf16x8 aC[2];
    #pragma unroll
    for (int nt = 0; nt < 2; ++nt) aC[nt] = *(const bf16x8*)(a_base + (size_t)nt * 16 * 512);
    asm volatile("s_waitcnt vmcnt(0)" ::: "memory");
    __syncthreads();
    #pragma unroll
    for (int tch = 0; tch < 4; ++tch) {
        const int cur = tch & 1;
        if (tch < 3) STAGE2(cur ^ 1, tch + 1)
        #pragma unroll
        for (int ks = 0; ks < 4; ++ks) {
            const int ksg = tch * 4 + ks;
            bf16x8 aN[2];
            if (ksg < 15) {
                #pragma unroll
                for (int nt = 0; nt < 2; ++nt)
                    aN[nt] = *(const bf16x8*)(a_base + (size_t)nt * 16 * 512 + (ksg + 1) * 32);
            }
            bf16x8 b[4];
            #pragma unroll
            for (int mt = 0; mt < 4; ++mt) {
                const int r = mt * 16 + l15;
                b[mt] = *(const bf16x8*)(&hb[cur][r * 128 + (((ks * 4 + quad) ^ l15) << 3)]);
            }
            #pragma unroll
            for (int nt = 0; nt < 2; ++nt)
                #pragma unroll
                for (int mt = 0; mt < 4; ++mt)
                    acc[nt][mt] = __builtin_amdgcn_mfma_f32_16x16x32_bf16(aC[nt], b[mt], acc[nt][mt], 0, 0, 0);
            if (ksg < 15) {
                #pragma unroll
                for (int nt = 0; nt < 2; ++nt) aC[nt] = aN[nt];
            }
        }
        if (tch < 3) {
            asm volatile("s_waitcnt vmcnt(0)" ::: "memory");
            __syncthreads();             // next chunk landed (all waves)
        }
    }
    #undef STAGE2
    // epilogue: lane holds out-channels chb..chb+3 for site m0+mt*16+l15
    #pragma unroll
    for (int nt = 0; nt < 2; ++nt) {
        const int chb = wn + nt * 16 + quad * 4;
        const float4 bev = *(const float4*)(b_eff + chb);
        const float4 b2v = *(const float4*)(b2 + chb);
        #pragma unroll
        for (int mt = 0; mt < 4; ++mt) {
            const int site = m0 + mt * 16 + l15;
            if (site < nsites) {
                const float4 fv = *(const float4*)(feats + (size_t)site * 128 + chb);
                float4 o;
                o.x = acc[nt][mt][0] + bev.x + b2v.x + fv.x;
                o.y = acc[nt][mt][1] + bev.y + b2v.y + fv.y;
                o.z = acc[nt][mt][2] + bev.z + b2v.z + fv.z;
                o.w = acc[nt][mt][3] + bev.w + b2v.w + fv.w;
                *(float4*)(out + (size_t)site * 128 + chb) = o;
            }
        }
    }
}

// ---------------------------------------------------------------------------
extern "C" void kernel_launch(void* const* d_in, const int* in_sizes, int n_in,
                              void* d_out, int out_size, void* d_ws, size_t ws_size,
                              hipStream_t stream) {
    const float* feats = (const float*)d_in[0];    // [N,128] f32
    const int* nb      = (const int*)d_in[1];      // [N,343] int32
    const float* dw_w  = (const float*)d_in[2];    // [343,128] f32
    const float* dw_b  = (const float*)d_in[3];    // [128]
    const float* ln_g  = (const float*)d_in[4];    // [128]
    const float* ln_b  = (const float*)d_in[5];    // [128]
    const float* w1    = (const float*)d_in[6];    // [128,512]
    const float* b1    = (const float*)d_in[7];    // [512]
    const float* grn_g = (const float*)d_in[8];    // [512]
    const float* grn_b = (const float*)d_in[9];    // [512]
    const float* w2    = (const float*)d_in[10];   // [512,128]
    const float* b2    = (const float*)d_in[11];   // [128]
    float* out = (float*)d_out;
    const int nsites = in_sizes[0] / 128;

    char* ws = (char*)d_ws;
    size_t off = 0;
    u16* xln   = (u16*)(ws + off);  off += (((size_t)(nsites + 128) * 128 * 2) + 255) & ~(size_t)255;
    u16* h     = (u16*)(ws + off);  off += (((size_t)(nsites + 128) * 512 * 2) + 255) & ~(size_t)255;
    u16* featsb= (u16*)(ws + off);  off += (((size_t)(nsites + 1) * 128 * 2) + 255) & ~(size_t)255;
    u16* dwwb  = (u16*)(ws + off);  off += 343 * 128 * 2 + 128;
    u16* w1t   = (u16*)(ws + off);  off += 512 * 128 * 2;
    u16* w2t   = (u16*)(ws + off);  off += 128 * 512 * 2;
    float* gx_sq = (float*)(ws + off); off += 512 * 4;
    float* scale = (float*)(ws + off); off += 512 * 4;
    float* b_eff = (float*)(ws + off); off += 128 * 4;

    hipMemsetAsync(gx_sq, 0, 512 * sizeof(float), stream);
    hipMemsetAsync(b_eff, 0, 128 * sizeof(float), stream);
    hipMemsetAsync(featsb + (size_t)nsites * 128, 0, 128 * sizeof(u16), stream);  // zero sentinel row
    const int nfeat4 = nsites * 32;
    cast_feats_k<<<(nfeat4 + 255) / 256, 256, 0, stream>>>(feats, featsb, nfeat4);
    const int ndww4 = 343 * 32;
    cast_feats_k<<<(ndww4 + 255) / 256, 256, 0, stream>>>(dw_w, dwwb, ndww4);
    transpose_w1_k<<<256, 256, 0, stream>>>(w1, w1t);
    beff_k<<<8, 256, 0, stream>>>(grn_b, w2, b_eff);
    dwln_k<<<(nsites + 3) / 4, 256, 0, stream>>>(featsb, nb, dwwb, dw_b, ln_g, ln_b, xln, nsites);
    const int nmb = (nsites + 63) / 64;
    const int gy = nmb < 256 ? nmb : 256;
    gemm1_k<<<dim3(4, gy), 256, 0, stream>>>(xln, w1t, b1, h, gx_sq, nsites, nmb);
    grn_scale_k<<<1, 512, 0, stream>>>(gx_sq, grn_g, scale);
    w2t_k<<<256, 256, 0, stream>>>(scale, w2, w2t);
    const int m2blocks = (nsites + 63) / 64;
    gemm2_k<<<m2blocks, 256, 0, stream>>>(h, w2t, b_eff, b2, feats, out, nsites);
}